// Round 1
// baseline (479.143 us; speedup 1.0000x reference)
//
#include <hip/hip_runtime.h>

#define Bn   32
#define Cn   17
#define Hn   96
#define Wn   72
#define Kn   3
#define KKn  9
#define PADn 1
#define HWn  (Hn * Wn)   // 6912

__global__ __launch_bounds__(256) void deform_conv_kernel(
    const float* __restrict__ x,
    const float* __restrict__ offsets,
    const float* __restrict__ mask,
    const float* __restrict__ weight,
    const float* __restrict__ bias,
    float* __restrict__ out)
{
    const int hw = blockIdx.x * blockDim.x + threadIdx.x;
    const int bc = blockIdx.y;            // b*C + c
    if (hw >= HWn) return;

    const int c = bc % Cn;
    const int h = hw / Wn;
    const int w = hw - h * Wn;

    const float* __restrict__ xp   = x       + (size_t)bc * HWn;
    const float* __restrict__ offp = offsets + (size_t)bc * (KKn * 2 * HWn) + hw;
    const float* __restrict__ mp   = mask    + (size_t)bc * (KKn * HWn) + hw;
    const float* __restrict__ wp   = weight  + c * KKn;

    float acc = bias[c];

    #pragma unroll
    for (int kk = 0; kk < KKn; ++kk) {
        const int ky = kk / Kn;
        const int kx = kk - ky * Kn;

        const float dy = offp[(size_t)(kk * 2 + 0) * HWn];
        const float dx = offp[(size_t)(kk * 2 + 1) * HWn];
        const float m  = mp[(size_t)kk * HWn];

        const float py = (float)(h - PADn + ky) + dy;
        const float px = (float)(w - PADn + kx) + dx;

        const float y0f = floorf(py);
        const float x0f = floorf(px);
        const float wy  = py - y0f;
        const float wx  = px - x0f;
        const int y0 = (int)y0f;
        const int x0 = (int)x0f;
        const int y1 = y0 + 1;
        const int x1 = x0 + 1;

        // clipped (always-safe) indices
        const int y0c = min(max(y0, 0), Hn - 1);
        const int y1c = min(max(y1, 0), Hn - 1);
        const int x0c = min(max(x0, 0), Wn - 1);
        const int x1c = min(max(x1, 0), Wn - 1);

        const bool vy0 = (y0 >= 0) & (y0 < Hn);
        const bool vy1 = (y1 >= 0) & (y1 < Hn);
        const bool vx0 = (x0 >= 0) & (x0 < Wn);
        const bool vx1 = (x1 >= 0) & (x1 < Wn);

        const float w00 = (vy0 & vx0) ? (1.f - wy) * (1.f - wx) : 0.f;
        const float w01 = (vy0 & vx1) ? (1.f - wy) * wx         : 0.f;
        const float w10 = (vy1 & vx0) ? wy * (1.f - wx)         : 0.f;
        const float w11 = (vy1 & vx1) ? wy * wx                 : 0.f;

        float v = 0.f;
        v += xp[y0c * Wn + x0c] * w00;
        v += xp[y0c * Wn + x1c] * w01;
        v += xp[y1c * Wn + x0c] * w10;
        v += xp[y1c * Wn + x1c] * w11;

        acc += v * m * wp[kk];
    }

    out[(size_t)bc * HWn + hw] = acc;
}

extern "C" void kernel_launch(void* const* d_in, const int* in_sizes, int n_in,
                              void* d_out, int out_size, void* d_ws, size_t ws_size,
                              hipStream_t stream) {
    const float* x       = (const float*)d_in[0];
    const float* offsets = (const float*)d_in[1];
    const float* mask    = (const float*)d_in[2];
    const float* weight  = (const float*)d_in[3];
    const float* bias    = (const float*)d_in[4];
    float* out = (float*)d_out;

    dim3 block(256, 1, 1);
    dim3 grid((HWn + 255) / 256, Bn * Cn, 1);
    deform_conv_kernel<<<grid, block, 0, stream>>>(x, offsets, mask, weight, bias, out);
}

// Round 2
// 461.385 us; speedup vs baseline: 1.0385x; 1.0385x over previous
//
#include <hip/hip_runtime.h>

#define Bn   32
#define Cn   17
#define Hn   96
#define Wn   72
#define Kn   3
#define KKn  9
#define PADn 1
#define HWn  (Hn * Wn)        // 6912
#define PX_PER_BLOCK 768      // 192 threads * 4 px
#define NBLK_X (HWn / PX_PER_BLOCK)  // 9

__global__ __launch_bounds__(192) void deform_conv_kernel(
    const float* __restrict__ x,
    const float* __restrict__ offsets,
    const float* __restrict__ mask,
    const float* __restrict__ weight,
    const float* __restrict__ bias,
    float* __restrict__ out)
{
    __shared__ float xs[HWn];   // whole (b,c) plane: 27648 B

    const int tid = threadIdx.x;
    const int bc  = blockIdx.y;              // b*C + c
    const int c   = bc % Cn;

    // ---- stage full x plane into LDS (coalesced float4) ----
    {
        const float4* __restrict__ xp4 = (const float4*)(x + (size_t)bc * HWn);
        float4* xs4 = (float4*)xs;
        #pragma unroll
        for (int j = 0; j < HWn / 4 / 192; ++j) {   // 9 iters
            const int i = j * 192 + tid;
            xs4[i] = xp4[i];
        }
    }
    __syncthreads();

    // ---- this thread's 4-pixel group ----
    const int hw = blockIdx.x * PX_PER_BLOCK + tid * 4;
    const int h  = hw / Wn;
    const int w  = hw - h * Wn;              // group never crosses a row (72 % 4 == 0)

    const float* __restrict__ offp = offsets + (size_t)bc * (KKn * 2 * HWn) + hw;
    const float* __restrict__ mp   = mask    + (size_t)bc * (KKn * HWn) + hw;
    const float* __restrict__ wp   = weight  + c * KKn;   // c uniform per block -> scalar

    const float bv = bias[c];
    float acc[4] = {bv, bv, bv, bv};

    #pragma unroll
    for (int kk = 0; kk < KKn; ++kk) {
        const float4 dy4 = *(const float4*)(offp + (size_t)(kk * 2 + 0) * HWn);
        const float4 dx4 = *(const float4*)(offp + (size_t)(kk * 2 + 1) * HWn);
        const float4 m4  = *(const float4*)(mp + (size_t)kk * HWn);
        const float  wk  = wp[kk];

        const int ky = kk / Kn;
        const int kx = kk - ky * Kn;
        const float base_y = (float)(h - PADn + ky);

        #pragma unroll
        for (int p = 0; p < 4; ++p) {
            const float dy = ((const float*)&dy4)[p];
            const float dx = ((const float*)&dx4)[p];
            const float m  = ((const float*)&m4)[p];

            const float py = base_y + dy;
            const float px = (float)(w + p - PADn + kx) + dx;

            const float y0f = floorf(py);
            const float x0f = floorf(px);
            const float wy  = py - y0f;
            const float wx  = px - x0f;
            const int y0 = (int)y0f;
            const int x0 = (int)x0f;
            const int y1 = y0 + 1;
            const int x1 = x0 + 1;

            const int y0c = min(max(y0, 0), Hn - 1);
            const int y1c = min(max(y1, 0), Hn - 1);
            const int x0c = min(max(x0, 0), Wn - 1);
            const int x1c = min(max(x1, 0), Wn - 1);

            const bool vy0 = (y0 >= 0) & (y0 < Hn);
            const bool vy1 = (y1 >= 0) & (y1 < Hn);
            const bool vx0 = (x0 >= 0) & (x0 < Wn);
            const bool vx1 = (x1 >= 0) & (x1 < Wn);

            const float w00 = (vy0 & vx0) ? (1.f - wy) * (1.f - wx) : 0.f;
            const float w01 = (vy0 & vx1) ? (1.f - wy) * wx         : 0.f;
            const float w10 = (vy1 & vx0) ? wy * (1.f - wx)         : 0.f;
            const float w11 = (vy1 & vx1) ? wy * wx                 : 0.f;

            float v = 0.f;
            v += xs[y0c * Wn + x0c] * w00;
            v += xs[y0c * Wn + x1c] * w01;
            v += xs[y1c * Wn + x0c] * w10;
            v += xs[y1c * Wn + x1c] * w11;

            acc[p] += v * m * wk;
        }
    }

    float4 o;
    o.x = acc[0]; o.y = acc[1]; o.z = acc[2]; o.w = acc[3];
    *(float4*)(out + (size_t)bc * HWn + hw) = o;
}

extern "C" void kernel_launch(void* const* d_in, const int* in_sizes, int n_in,
                              void* d_out, int out_size, void* d_ws, size_t ws_size,
                              hipStream_t stream) {
    const float* x       = (const float*)d_in[0];
    const float* offsets = (const float*)d_in[1];
    const float* mask    = (const float*)d_in[2];
    const float* weight  = (const float*)d_in[3];
    const float* bias    = (const float*)d_in[4];
    float* out = (float*)d_out;

    dim3 block(192, 1, 1);
    dim3 grid(NBLK_X, Bn * Cn, 1);
    deform_conv_kernel<<<grid, block, 0, stream>>>(x, offsets, mask, weight, bias, out);
}

// Round 3
// 460.245 us; speedup vs baseline: 1.0411x; 1.0025x over previous
//
#include <hip/hip_runtime.h>

#define Bn   32
#define Cn   17
#define Hn   96
#define Wn   72
#define Kn   3
#define KKn  9
#define PADn 1
#define HWn  (Hn * Wn)            // 6912
#define TPB  384                  // 6 waves
#define PX_PER_BLOCK (TPB * 2)    // 768
#define NBLK_X (HWn / PX_PER_BLOCK)  // 9

__global__ __launch_bounds__(TPB) void deform_conv_kernel(
    const float* __restrict__ x,
    const float* __restrict__ offsets,
    const float* __restrict__ mask,
    const float* __restrict__ weight,
    const float* __restrict__ bias,
    float* __restrict__ out)
{
    __shared__ float xs[HWn];   // 27648 B -> 5 blocks/CU

    const int tid = threadIdx.x;
    const int bc  = blockIdx.y;              // b*C + c
    const int c   = bc % Cn;

    // ---- stage full x plane into LDS (coalesced float2, 9 iters) ----
    {
        const float2* __restrict__ xp2 = (const float2*)(x + (size_t)bc * HWn);
        float2* xs2 = (float2*)xs;
        #pragma unroll
        for (int j = 0; j < HWn / 2 / TPB; ++j) {
            const int i = j * TPB + tid;
            xs2[i] = xp2[i];
        }
    }
    __syncthreads();

    // ---- this thread's 2-pixel group (never crosses a row: 72 % 2 == 0) ----
    const int hw = blockIdx.x * PX_PER_BLOCK + tid * 2;
    const int h  = hw / Wn;
    const int w  = hw - h * Wn;

    const float* __restrict__ offp = offsets + (size_t)bc * (KKn * 2 * HWn) + hw;
    const float* __restrict__ mp   = mask    + (size_t)bc * (KKn * HWn) + hw;
    const float* __restrict__ wp   = weight  + c * KKn;   // uniform per block -> scalar loads

    const float bv = bias[c];
    float acc0 = bv, acc1 = bv;

    #pragma unroll
    for (int kk = 0; kk < KKn; ++kk) {
        const float2 dy2 = *(const float2*)(offp + (size_t)(kk * 2 + 0) * HWn);
        const float2 dx2 = *(const float2*)(offp + (size_t)(kk * 2 + 1) * HWn);
        const float2 m2  = *(const float2*)(mp + (size_t)kk * HWn);
        const float  wk  = wp[kk];

        const int ky = kk / Kn;
        const int kx = kk - ky * Kn;
        const float base_y = (float)(h - PADn + ky);

        #pragma unroll
        for (int p = 0; p < 2; ++p) {
            const float dy = p ? dy2.y : dy2.x;
            const float dx = p ? dx2.y : dx2.x;
            const float m  = p ? m2.y  : m2.x;

            const float py = base_y + dy;
            const float px = (float)(w + p - PADn + kx) + dx;

            const float y0f = floorf(py);
            const float x0f = floorf(px);
            const float wy  = py - y0f;
            const float wx  = px - x0f;
            const int y0 = (int)y0f;
            const int x0 = (int)x0f;
            const int y1 = y0 + 1;
            const int x1 = x0 + 1;

            const int y0c = min(max(y0, 0), Hn - 1);
            const int y1c = min(max(y1, 0), Hn - 1);
            const int x0c = min(max(x0, 0), Wn - 1);
            const int x1c = min(max(x1, 0), Wn - 1);

            // zero-masked 1-D weight components (w00 = wy0*wx0 etc.)
            const float wy0 = (y0 == y0c) ? (1.f - wy) : 0.f;  // y0 in [0,H-1] iff clamp is identity
            const float wy1 = (y1 == y1c) ? wy         : 0.f;
            const float wx0 = (x0 == x0c) ? (1.f - wx) : 0.f;
            const float wx1 = (x1 == x1c) ? wx         : 0.f;

            const int r0 = y0c * Wn;
            const int r1 = y1c * Wn;
            const float row0 = xs[r0 + x0c] * wx0 + xs[r0 + x1c] * wx1;
            const float row1 = xs[r1 + x0c] * wx0 + xs[r1 + x1c] * wx1;
            const float v    = row0 * wy0 + row1 * wy1;

            const float mw = m * wk;
            if (p) acc1 += v * mw; else acc0 += v * mw;
        }
    }

    float2 o; o.x = acc0; o.y = acc1;
    *(float2*)(out + (size_t)bc * HWn + hw) = o;
}

extern "C" void kernel_launch(void* const* d_in, const int* in_sizes, int n_in,
                              void* d_out, int out_size, void* d_ws, size_t ws_size,
                              hipStream_t stream) {
    const float* x       = (const float*)d_in[0];
    const float* offsets = (const float*)d_in[1];
    const float* mask    = (const float*)d_in[2];
    const float* weight  = (const float*)d_in[3];
    const float* bias    = (const float*)d_in[4];
    float* out = (float*)d_out;

    dim3 block(TPB, 1, 1);
    dim3 grid(NBLK_X, Bn * Cn, 1);
    deform_conv_kernel<<<grid, block, 0, stream>>>(x, offsets, mask, weight, bias, out);
}

// Round 4
// 459.412 us; speedup vs baseline: 1.0429x; 1.0018x over previous
//
#include <hip/hip_runtime.h>

#define Bn   32
#define Cn   17
#define Hn   96
#define Wn   72
#define Kn   3
#define KKn  9
#define PADn 1
#define HWn  (Hn * Wn)            // 6912
#define TPB  576                  // 9 waves
#define ROWS_PER_BLOCK 32
#define PX_PER_BLOCK (ROWS_PER_BLOCK * Wn)   // 2304
#define NBLK_X (Hn / ROWS_PER_BLOCK)         // 3
#define NPX  4                    // pixels per thread, stride TPB (= 8 rows)

__global__ __launch_bounds__(TPB) void deform_conv_kernel(
    const float* __restrict__ x,
    const float* __restrict__ offsets,
    const float* __restrict__ mask,
    const float* __restrict__ weight,
    const float* __restrict__ bias,
    float* __restrict__ out)
{
    __shared__ float xs[HWn];   // full (b,c) plane: 27648 B

    const int tid = threadIdx.x;
    const int bc  = blockIdx.y;              // b*C + c
    const int c   = bc % Cn;

    // ---- stage full x plane into LDS once per block (coalesced float4, 3 iters) ----
    {
        const float4* __restrict__ xp4 = (const float4*)(x + (size_t)bc * HWn);
        float4* xs4 = (float4*)xs;
        #pragma unroll
        for (int j = 0; j < HWn / 4 / TPB; ++j) {   // 3 iters
            const int i = j * TPB + tid;
            xs4[i] = xp4[i];
        }
    }
    __syncthreads();

    // ---- this thread's 4 pixels: same w, rows h0 + 8p (lanes w-consecutive) ----
    const int w  = tid % Wn;
    const int h0 = blockIdx.x * ROWS_PER_BLOCK + tid / Wn;   // tid/Wn in [0,8)

    const float* __restrict__ offp = offsets + (size_t)bc * (KKn * 2 * HWn);
    const float* __restrict__ mp   = mask    + (size_t)bc * (KKn * HWn);
    const float* __restrict__ wp   = weight  + c * KKn;   // uniform per block -> scalar loads

    const float bv = bias[c];
    float acc[NPX] = {bv, bv, bv, bv};

    // base hw index for p=0; each p adds 8 rows = 8*Wn
    const int hw0 = h0 * Wn + w;

    #pragma unroll
    for (int kk = 0; kk < KKn; ++kk) {
        const float wk = wp[kk];
        const int ky = kk / Kn;
        const int kx = kk - ky * Kn;

        // issue all 12 streaming loads for this kk first (coalesced dwords)
        float dyv[NPX], dxv[NPX], mv[NPX];
        #pragma unroll
        for (int p = 0; p < NPX; ++p) {
            const int hw_p = hw0 + p * 8 * Wn;
            dyv[p] = offp[(size_t)(kk * 2 + 0) * HWn + hw_p];
            dxv[p] = offp[(size_t)(kk * 2 + 1) * HWn + hw_p];
            mv[p]  = mp[(size_t)kk * HWn + hw_p];
        }

        #pragma unroll
        for (int p = 0; p < NPX; ++p) {
            const int hp = h0 + 8 * p;

            const float py = (float)(hp - PADn + ky) + dyv[p];
            const float px = (float)(w  - PADn + kx) + dxv[p];

            const float y0f = floorf(py);
            const float x0f = floorf(px);
            const float wy  = py - y0f;
            const float wx  = px - x0f;
            const int y0 = (int)y0f;
            const int x0 = (int)x0f;
            const int y1 = y0 + 1;
            const int x1 = x0 + 1;

            const int y0c = min(max(y0, 0), Hn - 1);
            const int y1c = min(max(y1, 0), Hn - 1);
            const int x0c = min(max(x0, 0), Wn - 1);
            const int x1c = min(max(x1, 0), Wn - 1);

            // zero-masked 1-D weight components
            const float wy0 = (y0 == y0c) ? (1.f - wy) : 0.f;
            const float wy1 = (y1 == y1c) ? wy         : 0.f;
            const float wx0 = (x0 == x0c) ? (1.f - wx) : 0.f;
            const float wx1 = (x1 == x1c) ? wx         : 0.f;

            const int r0 = y0c * Wn;
            const int r1 = y1c * Wn;
            const float row0 = xs[r0 + x0c] * wx0 + xs[r0 + x1c] * wx1;
            const float row1 = xs[r1 + x0c] * wx0 + xs[r1 + x1c] * wx1;
            const float v    = row0 * wy0 + row1 * wy1;

            acc[p] += v * (mv[p] * wk);
        }
    }

    const size_t ob = (size_t)bc * HWn;
    #pragma unroll
    for (int p = 0; p < NPX; ++p) {
        out[ob + hw0 + p * 8 * Wn] = acc[p];
    }
}

extern "C" void kernel_launch(void* const* d_in, const int* in_sizes, int n_in,
                              void* d_out, int out_size, void* d_ws, size_t ws_size,
                              hipStream_t stream) {
    const float* x       = (const float*)d_in[0];
    const float* offsets = (const float*)d_in[1];
    const float* mask    = (const float*)d_in[2];
    const float* weight  = (const float*)d_in[3];
    const float* bias    = (const float*)d_in[4];
    float* out = (float*)d_out;

    dim3 block(TPB, 1, 1);
    dim3 grid(NBLK_X, Bn * Cn, 1);
    deform_conv_kernel<<<grid, block, 0, stream>>>(x, offsets, mask, weight, bias, out);
}